// Round 11
// baseline (2436.763 us; speedup 1.0000x reference)
//
#include <hip/hip_runtime.h>
#include <hip/hip_bf16.h>
#include <stdint.h>

#define DEV __device__ __forceinline__

typedef __bf16 bf16;
typedef __attribute__((ext_vector_type(8))) __bf16 bf16x8;
typedef __attribute__((ext_vector_type(4))) float f32x4;
typedef __attribute__((ext_vector_type(4))) unsigned short u16x4;

constexpr int Bb = 128, Tt = 199, Ee = 256, Hh = 256;
constexpr int Mm = Bb * Tt;       // 25472
constexpr int G4 = 4 * Hh;        // 1024 gate rows

// ---------------- workspace layout (bytes) ----------------
constexpr size_t OFF_WLI_H = 0;
constexpr size_t OFF_WLI_L = OFF_WLI_H + (size_t)Hh * 768 * 2;
constexpr size_t OFF_WIH_H = OFF_WLI_L + (size_t)Hh * 768 * 2;
constexpr size_t OFF_WIH_L = OFF_WIH_H + (size_t)G4 * Hh * 2;
constexpr size_t OFF_WNF_H = OFF_WIH_L + (size_t)G4 * Hh * 2;
constexpr size_t OFF_WNF_L = OFF_WNF_H + (size_t)Hh * Ee * 2;
constexpr size_t OFF_WHB   = OFF_WNF_L + (size_t)Hh * Ee * 2;   // whh bf16 [1024][256]
constexpr size_t OFF_OFP   = OFF_WHB   + (size_t)G4 * Hh * 2;   // frag-packed o rows (256x256 bf16)
constexpr size_t OFF_XIN_H = OFF_OFP   + (size_t)256 * Hh * 2;
constexpr size_t OFF_XIN_L = OFF_XIN_H + (size_t)Mm * Hh * 2;
constexpr size_t OFF_XPH   = OFF_XIN_L + (size_t)Mm * Hh * 2;   // xp bf16 [t][bgrp 8][n 1024][bi 16]
constexpr size_t OFF_HEX   = OFF_XPH   + (size_t)Mm * G4 * 2;   // f32 [g][t][16][256]
constexpr size_t OFF_NTR   = OFF_HEX   + (size_t)Mm * Hh * 4;   // f32 [t*128+b][256]
constexpr size_t WS_NEED   = OFF_NTR   + (size_t)Mm * Hh * 4;   // ~133 MiB

DEV float sigm(float x)  { return 1.0f / (1.0f + __expf(-x)); }
DEV float tanh_(float x) { return 2.0f / (1.0f + __expf(-2.0f * x)) - 1.0f; }
DEV float b2f(unsigned short u) { return __uint_as_float(((unsigned)u) << 16); }
DEV unsigned short f2bbits(bf16 h) { union { bf16 b; unsigned short u; } cv; cv.b = h; return cv.u; }

#define MFMA16(a, b, c) __builtin_amdgcn_mfma_f32_16x16x32_bf16(a, b, c, 0, 0, 0)

// ============================================================
// k_prep: weights -> bf16 hi/lo pairs; whh -> plain bf16 + frag-packed o
// ============================================================
__global__ void k_prep(const float* __restrict__ Wli, const float* __restrict__ Wih,
                       const float* __restrict__ Wnf, const float* __restrict__ Whh,
                       bf16* wli_h, bf16* wli_l, bf16* wih_h, bf16* wih_l,
                       bf16* wnf_h, bf16* wnf_l, bf16* whb, bf16* ofp) {
    const int n1 = Hh * 768, n2 = G4 * Hh, n3 = Hh * Ee, n4 = G4 * Hh;
    const int ntot = n1 + n2 + n3 + n4;
    for (int idx = blockIdx.x * 256 + threadIdx.x; idx < ntot; idx += gridDim.x * 256) {
        if (idx < n1 + n2 + n3) {
            const float* src; bf16 *dh, *dl; int j;
            if (idx < n1)           { src = Wli; dh = wli_h; dl = wli_l; j = idx; }
            else if (idx < n1 + n2) { src = Wih; dh = wih_h; dl = wih_l; j = idx - n1; }
            else                    { src = Wnf; dh = wnf_h; dl = wnf_l; j = idx - n1 - n2; }
            float x = src[j];
            bf16 h = (bf16)x;
            dh[j] = h;
            dl[j] = (bf16)(x - (float)h);
        } else {
            int j = idx - n1 - n2 - n3;          // whh flat index
            int row = j >> 8, k = j & 255;
            bf16 v = (bf16)Whh[j];
            whb[j] = v;
            if (row >= 768) {                    // o-gate rows -> frag-packed tiles
                int rr = row - 768;
                int T  = rr >> 4, lr = rr & 15;  // unit tile 0..15
                int kt = k >> 5, lh = (k >> 3) & 3, jj = k & 7;
                size_t o = (((size_t)T * 8 + kt) * 64 + lh * 16 + lr) * 8 + jj;
                ofp[o] = v;
            }
        }
    }
}

// ============================================================
// k_gemm: split-bf16 (3-pass) 128x128x64-tile GEMM, 4 waves. (unchanged)
// ============================================================
template<int AMODE, int EPI, int KT, int NTOT>
__global__ __launch_bounds__(256, 2)
void k_gemm(const float* __restrict__ a0, const float* __restrict__ a1,
            const float* __restrict__ a2,
            const bf16* __restrict__ ah_src, const bf16* __restrict__ al_src,
            const bf16* __restrict__ bh_src, const bf16* __restrict__ bl_src,
            const float* __restrict__ bias0, const float* __restrict__ bias1,
            float* __restrict__ outf, bf16* __restrict__ outh, bf16* __restrict__ outl)
{
    __shared__ __align__(16) bf16 lA[2][128 * 64];
    __shared__ __align__(16) bf16 lB[2][128 * 64];
    const int tid = threadIdx.x;
    const int l = tid & 63, w = tid >> 6;
    const int wr = w >> 1, wc = w & 1;
    const int lr = l & 15, lh = l >> 4;
    const int mb = blockIdx.x;
    const int nb = blockIdx.y;

    f32x4 acc[4][4];
    #pragma unroll
    for (int i = 0; i < 4; ++i)
        #pragma unroll
        for (int j = 0; j < 4; ++j) acc[i][j] = {};

    for (int ks = 0; ks < KT / 64; ++ks) {
        #pragma unroll
        for (int p = 0; p < 4; ++p) {
            int Gi = p * 256 + tid;
            int row = Gi >> 3, gsl = Gi & 7;
            int k = ks * 64 + gsl * 8;
            int dst = row * 64 + ((gsl ^ (row & 7)) * 8);
            if constexpr (AMODE == 2) {
                size_t base = (size_t)(mb * 128 + row) * KT + k;
                *(bf16x8*)&lA[0][dst] = *(const bf16x8*)(ah_src + base);
                *(bf16x8*)&lA[1][dst] = *(const bf16x8*)(al_src + base);
            } else {
                const float* src; int e;
                if constexpr (AMODE == 0) {
                    int seg = k >> 8; e = k & 255;
                    src = (seg == 0) ? a0 : (seg == 1) ? a1 : a2;
                } else { src = a0; e = k; }
                size_t base = ((size_t)row * Tt + mb) * Ee + e;
                float4 v0 = *(const float4*)(src + base);
                float4 v1 = *(const float4*)(src + base + 4);
                float vv[8] = {v0.x, v0.y, v0.z, v0.w, v1.x, v1.y, v1.z, v1.w};
                bf16x8 hv, lv;
                #pragma unroll
                for (int j = 0; j < 8; ++j) {
                    bf16 h = (bf16)vv[j];
                    hv[j] = h;
                    lv[j] = (bf16)(vv[j] - (float)h);
                }
                *(bf16x8*)&lA[0][dst] = hv;
                *(bf16x8*)&lA[1][dst] = lv;
            }
            size_t bbase = (size_t)(nb * 128 + row) * KT + k;
            *(bf16x8*)&lB[0][dst] = *(const bf16x8*)(bh_src + bbase);
            *(bf16x8*)&lB[1][dst] = *(const bf16x8*)(bl_src + bbase);
        }
        __syncthreads();
        #pragma unroll
        for (int kt = 0; kt < 2; ++kt) {
            bf16x8 ah[4], al[4], bh[4], bl[4];
            #pragma unroll
            for (int mt = 0; mt < 4; ++mt) {
                int row = wr * 64 + mt * 16 + lr;
                int g = (kt * 4 + lh) ^ (row & 7);
                ah[mt] = *(const bf16x8*)&lA[0][row * 64 + g * 8];
                al[mt] = *(const bf16x8*)&lA[1][row * 64 + g * 8];
            }
            #pragma unroll
            for (int nt = 0; nt < 4; ++nt) {
                int row = wc * 64 + nt * 16 + lr;
                int g = (kt * 4 + lh) ^ (row & 7);
                bh[nt] = *(const bf16x8*)&lB[0][row * 64 + g * 8];
                bl[nt] = *(const bf16x8*)&lB[1][row * 64 + g * 8];
            }
            #pragma unroll
            for (int mt = 0; mt < 4; ++mt)
                #pragma unroll
                for (int nt = 0; nt < 4; ++nt) {
                    acc[mt][nt] = MFMA16(ah[mt], bh[nt], acc[mt][nt]);
                    acc[mt][nt] = MFMA16(ah[mt], bl[nt], acc[mt][nt]);
                    acc[mt][nt] = MFMA16(al[mt], bh[nt], acc[mt][nt]);
                }
        }
        __syncthreads();
    }
    if constexpr (EPI == 1) {
        // packed store: xph[((t*8 + bgrp)*1024 + n)*16 + bi], contiguous 512B/wave
        #pragma unroll
        for (int nt = 0; nt < 4; ++nt) {
            int n = nb * 128 + wc * 64 + nt * 16 + lr;
            float bv = bias0[n] + bias1[n];
            #pragma unroll
            for (int mt = 0; mt < 4; ++mt) {
                int bq = wr * 4 + mt;
                u16x4 pk;
                #pragma unroll
                for (int r = 0; r < 4; ++r)
                    pk[r] = f2bbits((bf16)(acc[mt][nt][r] + bv));
                *(u16x4*)(outh + (((size_t)mb * 8 + bq) * 1024 + n) * 16 + lh * 4) = pk;
            }
        }
    } else {
        #pragma unroll
        for (int nt = 0; nt < 4; ++nt) {
            int n = nb * 128 + wc * 64 + nt * 16 + lr;
            float bv = bias0[n];
            #pragma unroll
            for (int mt = 0; mt < 4; ++mt)
                #pragma unroll
                for (int r = 0; r < 4; ++r) {
                    int m = mb * 128 + wr * 64 + mt * 16 + lh * 4 + r;
                    float v = acc[mt][nt][r] + bv;
                    if constexpr (EPI == 0) {
                        bf16 h = (bf16)v;
                        outh[(size_t)m * NTOT + n] = h;
                        outl[(size_t)m * NTOT + n] = (bf16)(v - (float)h);
                    } else {
                        outf[(size_t)m * NTOT + n] = fmaxf(v, 0.f);
                    }
                }
        }
    }
}

// ============================================================
// k_lstm: 8 WGs x 256 threads (4 waves, __launch_bounds__(256,1) -> 1
// wave/SIMD -> 512 unified regs/wave). Live set ~470 <= 512, so the
// allocator has NO pressure reason to rematerialize (rounds 8-10 failure
// mode). Wave w owns units [64w,64w+64) (4 tiles of 16), all 4 gates.
// i,f resident in 256 plain VGPR-class regs; g fully in LDS (128 KB,
// rotation swizzle); o streamed frag-packed from L2 with DEPTH-4 prefetch
// (~400cyc cover > L2 latency); xq issued at kt==4. h double-buffered in
// LDS; ONE raw lgkmcnt-only barrier per step.
// ============================================================
__global__ __launch_bounds__(256, 1)
void k_lstm(const bf16* __restrict__ whb, const bf16* __restrict__ ofp,
            const bf16* __restrict__ xph, float* __restrict__ hexch)
{
    __shared__ __align__(16) bf16 lds_g[256 * 256];   // 128KB: all g-gate rows
    __shared__ __align__(16) bf16 hbuf[2][16 * 256];  // 16KB: h double buffer
    const int tid = threadIdx.x;
    const int l = tid & 63, w = tid >> 6;             // wave 0..3
    const int lr = l & 15, lh = l >> 4;
    const int g = blockIdx.x;                         // batch group 0..7

    // ---- resident i,f gate B-frags: 256 regs ----
    f32x4 wfi[4][8], wff[4][8];
    #pragma unroll
    for (int u = 0; u < 4; ++u)
        #pragma unroll
        for (int kt = 0; kt < 8; ++kt) {
            int row = 64 * w + 16 * u + lr;
            wfi[u][kt] = *(const f32x4*)(whb + (size_t)row * 256 + kt * 32 + lh * 8);
            wff[u][kt] = *(const f32x4*)(whb + (size_t)(256 + row) * 256 + kt * 32 + lh * 8);
        }

    // ---- stage ALL g-gate rows (whb rows 512..767) into LDS ----
    #pragma unroll
    for (int it = 0; it < 32; ++it) {
        int G = it * 256 + tid;                // 8192 granules of 16B
        int r = G >> 5, gk = G & 31;
        *(bf16x8*)&lds_g[r * 256 + ((gk + r) & 31) * 8] =
            *(const bf16x8*)(whb + (size_t)(512 + r) * 256 + gk * 8);
    }
    __syncthreads();

    f32x4 cst[4] = {};

    for (int t = 0; t < Tt; ++t) {
        const bf16* xb = xph + (size_t)(t * 8 + g) * 1024 * 16;
        u16x4 xq[4][4];

        f32x4 acc[4][4];
        #pragma unroll
        for (int q = 0; q < 4; ++q)
            #pragma unroll
            for (int u = 0; u < 4; ++u) acc[q][u] = {};

        if (t > 0) {
            const bf16* hb = hbuf[(t - 1) & 1];
            // depth-4 o-prefetch ring: 64 regs
            bf16x8 ost[4][4];
            #pragma unroll
            for (int p = 0; p < 4; ++p)
                #pragma unroll
                for (int u = 0; u < 4; ++u) {
                    int T = w * 4 + u;
                    ost[p][u] = *(const bf16x8*)(ofp + (((size_t)T * 8 + p) * 64 + l) * 8);
                }
            #pragma unroll
            for (int kt = 0; kt < 8; ++kt) {
                bf16x8 af = *(const bf16x8*)&hb[lr * 256 + ((kt * 4 + lh + lr) & 31) * 8];
                if (kt == 4) {   // xq issue: latency covered by kt=4..7 MFMA work
                    #pragma unroll
                    for (int gate = 0; gate < 4; ++gate)
                        #pragma unroll
                        for (int u = 0; u < 4; ++u) {
                            int n = gate * 256 + 64 * w + 16 * u + lr;
                            xq[gate][u] = *(const u16x4*)(xb + (size_t)n * 16 + lh * 4);
                        }
                }
                #pragma unroll
                for (int u = 0; u < 4; ++u) {
                    int r0 = 64 * w + 16 * u + lr;
                    bf16x8 gg = *(const bf16x8*)&lds_g[r0 * 256 + ((kt * 4 + lh + r0) & 31) * 8];
                    acc[0][u] = MFMA16(af, __builtin_bit_cast(bf16x8, wfi[u][kt]), acc[0][u]);
                    acc[1][u] = MFMA16(af, __builtin_bit_cast(bf16x8, wff[u][kt]), acc[1][u]);
                    acc[2][u] = MFMA16(af, gg, acc[2][u]);
                    acc[3][u] = MFMA16(af, ost[kt & 3][u], acc[3][u]);
                }
                if (kt < 4) {
                    #pragma unroll
                    for (int u = 0; u < 4; ++u) {
                        int T = w * 4 + u;
                        ost[kt & 3][u] = *(const bf16x8*)(ofp + (((size_t)T * 8 + (kt + 4)) * 64 + l) * 8);
                    }
                }
            }
        } else {
            #pragma unroll
            for (int gate = 0; gate < 4; ++gate)
                #pragma unroll
                for (int u = 0; u < 4; ++u) {
                    int n = gate * 256 + 64 * w + 16 * u + lr;
                    xq[gate][u] = *(const u16x4*)(xb + (size_t)n * 16 + lh * 4);
                }
        }

        // ---- in-register update; h -> LDS (bf16, swizzled) + global (f32) ----
        float* hg = hexch + (size_t)(g * Tt + t) * 16 * 256;
        bf16* hw = hbuf[t & 1];
        #pragma unroll
        for (int u = 0; u < 4; ++u) {
            int j = 64 * w + 16 * u + lr;
            int gj = j >> 3, j7 = j & 7;
            #pragma unroll
            for (int r = 0; r < 4; ++r) {
                float iv = acc[0][u][r] + b2f(xq[0][u][r]);
                float fv = acc[1][u][r] + b2f(xq[1][u][r]);
                float gv = acc[2][u][r] + b2f(xq[2][u][r]);
                float ov = acc[3][u][r] + b2f(xq[3][u][r]);
                float cn = sigm(fv) * cst[u][r] + sigm(iv) * tanh_(gv);
                cst[u][r] = cn;
                float hv = sigm(ov) * tanh_(cn);
                int m = lh * 4 + r;
                hg[(size_t)m * 256 + j] = hv;
                hw[m * 256 + ((gj + m) & 31) * 8 + j7] = (bf16)hv;
            }
        }
        // ONE barrier per step: LDS ordering only (don't drain h global stores)
        asm volatile("s_waitcnt lgkmcnt(0)\n\ts_barrier" ::: "memory");
    }
}

// ============================================================
// k_attn: one wave per (b,t). 9 dot products + att softmax, all f32.
// ============================================================
DEV float wred(float v) {
    #pragma unroll
    for (int off = 32; off > 0; off >>= 1) v += __shfl_down(v, off, 64);
    return v;
}

__global__ __launch_bounds__(256, 4)
void k_attn(const float* __restrict__ hexch, const float* __restrict__ ntr,
            const int* __restrict__ hidx,
            const float* __restrict__ a1w, const float* __restrict__ a1b,
            const float* __restrict__ a2w, const float* __restrict__ a2b,
            float* __restrict__ out)
{
    int wid = blockIdx.x * 4 + (threadIdx.x >> 6);
    if (wid >= Mm) return;
    int l = threadIdx.x & 63;
    int t = wid / Bb, b = wid % Bb;
    int g = b >> 4, bi = b & 15;

    float4 nt4 = *(const float4*)(ntr + (size_t)wid * 256 + l * 4);
    float4 w14 = *(const float4*)(a1w + l * 4);
    float4 w24 = *(const float4*)(a2w + l * 4);
    float lg[9], fh[9];
    float fn = nt4.x * w24.x + nt4.y * w24.y + nt4.z * w24.z + nt4.w * w24.w;
    #pragma unroll
    for (int k = 0; k < 9; ++k) {
        int ts = (k == 0) ? t : hidx[((size_t)b * Tt + t) * 8 + (k - 1)];
        const float* hrow = hexch + ((size_t)(g * Tt + ts) * 16 + bi) * 256;
        float4 h4 = *(const float4*)(hrow + l * 4);
        lg[k] = h4.x * nt4.x + h4.y * nt4.y + h4.z * nt4.z + h4.w * nt4.w;
        fh[k] = h4.x * w14.x + h4.y * w14.y + h4.z * w14.z + h4.w * w14.w;
    }
    #pragma unroll
    for (int k = 0; k < 9; ++k) { lg[k] = wred(lg[k]); fh[k] = wred(fh[k]); }
    fn = wred(fn);
    if (l == 0) {
        float f2 = fn + a2b[0], b1 = a1b[0];
        float tv[9], mx = -1e30f;
        #pragma unroll
        for (int k = 0; k < 9; ++k) { tv[k] = tanh_(fh[k] + b1 + f2); mx = fmaxf(mx, tv[k]); }
        float s = 0.f, accv = 0.f;
        #pragma unroll
        for (int k = 0; k < 9; ++k) { float e = __expf(tv[k] - mx); s += e; accv += e * lg[k]; }
        out[(size_t)b * Tt + t] = accv / s;
    }
}

// ============================================================
extern "C" void kernel_launch(void* const* d_in, const int* in_sizes, int n_in,
                              void* d_out, int out_size, void* d_ws, size_t ws_size,
                              hipStream_t stream)
{
    const float* q   = (const float*)d_in[0];
    const float* nq  = (const float*)d_in[1];
    const float* sk  = (const float*)d_in[2];
    const float* an  = (const float*)d_in[3];
    const int*   hid = (const int*)d_in[4];
    const float* Wnf = (const float*)d_in[5];
    const float* bnf = (const float*)d_in[6];
    const float* Wli = (const float*)d_in[7];
    const float* bli = (const float*)d_in[8];
    const float* Wih = (const float*)d_in[9];
    const float* Whh = (const float*)d_in[10];
    const float* bih = (const float*)d_in[11];
    const float* bhh = (const float*)d_in[12];
    const float* a1w = (const float*)d_in[13];
    const float* a1b = (const float*)d_in[14];
    const float* a2w = (const float*)d_in[15];
    const float* a2b = (const float*)d_in[16];
    float* out = (float*)d_out;

    char* ws = (char*)d_ws;   // needs ~133 MiB (WS_NEED)
    bf16* wli_h = (bf16*)(ws + OFF_WLI_H);
    bf16* wli_l = (bf16*)(ws + OFF_WLI_L);
    bf16* wih_h = (bf16*)(ws + OFF_WIH_H);
    bf16* wih_l = (bf16*)(ws + OFF_WIH_L);
    bf16* wnf_h = (bf16*)(ws + OFF_WNF_H);
    bf16* wnf_l = (bf16*)(ws + OFF_WNF_L);
    bf16* whb   = (bf16*)(ws + OFF_WHB);
    bf16* ofp   = (bf16*)(ws + OFF_OFP);
    bf16* xin_h = (bf16*)(ws + OFF_XIN_H);
    bf16* xin_l = (bf16*)(ws + OFF_XIN_L);
    bf16* xph   = (bf16*)(ws + OFF_XPH);
    float* hex  = (float*)(ws + OFF_HEX);
    float* ntr  = (float*)(ws + OFF_NTR);

    k_prep<<<512, 256, 0, stream>>>(Wli, Wih, Wnf, Whh, wli_h, wli_l, wih_h, wih_l,
                                    wnf_h, wnf_l, whb, ofp);

    // x_in (hi/lo) = [q|ans|skill] @ W_li^T + b_li     (M x 256, K=768)
    dim3 g1(Tt, 2);
    k_gemm<0, 0, 768, 256><<<g1, 256, 0, stream>>>(q, an, sk, nullptr, nullptr,
        wli_h, wli_l, bli, nullptr, nullptr, xin_h, xin_l);

    // xp(bf16) = x_in @ W_ih^T + (b_ih + b_hh), packed [t][bgrp][n][16]
    dim3 g2(Tt, 8);
    k_gemm<2, 1, 256, 1024><<<g2, 256, 0, stream>>>(nullptr, nullptr, nullptr, xin_h, xin_l,
        wih_h, wih_l, bih, bhh, nullptr, xph, nullptr);

    // next_trans = relu(nq @ W_nf^T + b_nf)            (M x 256, K=256)
    dim3 g3(Tt, 2);
    k_gemm<1, 2, 256, 256><<<g3, 256, 0, stream>>>(nq, nullptr, nullptr, nullptr, nullptr,
        wnf_h, wnf_l, bnf, nullptr, ntr, nullptr, nullptr);

    k_lstm<<<8, 256, 0, stream>>>(whb, ofp, xph, hex);

    k_attn<<<Mm / 4, 256, 0, stream>>>(hex, ntr, hid, a1w, a1b, a2w, a2b, out);
    (void)in_sizes; (void)n_in; (void)out_size; (void)ws_size;
}

// Round 12
// 809.157 us; speedup vs baseline: 3.0115x; 3.0115x over previous
//
#include <hip/hip_runtime.h>
#include <hip/hip_bf16.h>
#include <stdint.h>

#define DEV __device__ __forceinline__

typedef __bf16 bf16;
typedef __attribute__((ext_vector_type(8))) __bf16 bf16x8;
typedef __attribute__((ext_vector_type(4))) float f32x4;
typedef __attribute__((ext_vector_type(4))) unsigned short u16x4;

constexpr int Bb = 128, Tt = 199, Ee = 256, Hh = 256;
constexpr int Mm = Bb * Tt;       // 25472
constexpr int G4 = 4 * Hh;        // 1024 gate rows

// ---------------- workspace layout (bytes) ----------------
constexpr size_t OFF_FLAGS = 0;                                 // 32 flags @64B stride
constexpr size_t OFF_WLI_H = 8192;
constexpr size_t OFF_WLI_L = OFF_WLI_H + (size_t)Hh * 768 * 2;
constexpr size_t OFF_WIH_H = OFF_WLI_L + (size_t)Hh * 768 * 2;
constexpr size_t OFF_WIH_L = OFF_WIH_H + (size_t)G4 * Hh * 2;
constexpr size_t OFF_WNF_H = OFF_WIH_L + (size_t)G4 * Hh * 2;
constexpr size_t OFF_WNF_L = OFF_WNF_H + (size_t)Hh * Ee * 2;
constexpr size_t OFF_WHB   = OFF_WNF_L + (size_t)Hh * Ee * 2;   // whh bf16 [1024][256]
constexpr size_t OFF_XIN_H = OFF_WHB   + (size_t)G4 * Hh * 2;
constexpr size_t OFF_XIN_L = OFF_XIN_H + (size_t)Mm * Hh * 2;
constexpr size_t OFF_XPH   = OFF_XIN_L + (size_t)Mm * Hh * 2;   // xp bf16 [t][bgrp 8][n 1024][bi 16]
constexpr size_t OFF_HEX   = OFF_XPH   + (size_t)Mm * G4 * 2;   // f32 [g][t][16][256]
constexpr size_t OFF_NTR   = OFF_HEX   + (size_t)Mm * Hh * 4;   // f32 [t*128+b][256]
constexpr size_t WS_NEED   = OFF_NTR   + (size_t)Mm * Hh * 4;   // ~133 MiB

DEV float sigm(float x)  { return 1.0f / (1.0f + __expf(-x)); }
DEV float tanh_(float x) { return 2.0f / (1.0f + __expf(-2.0f * x)) - 1.0f; }
DEV float b2f(unsigned short u) { return __uint_as_float(((unsigned)u) << 16); }
DEV unsigned short f2bbits(bf16 h) { union { bf16 b; unsigned short u; } cv; cv.b = h; return cv.u; }

#define MFMA16(a, b, c) __builtin_amdgcn_mfma_f32_16x16x32_bf16(a, b, c, 0, 0, 0)

// ============================================================
// k_reset: zero the 32 lstm sync flags (every launch, before k_lstm)
// ============================================================
__global__ void k_reset(unsigned int* flags) {
    int i = blockIdx.x * 256 + threadIdx.x;
    if (i < 32 * 16) flags[i] = 0;
}

// ============================================================
// k_prep: weights -> bf16 hi/lo pairs; whh -> plain bf16 copy
// ============================================================
__global__ void k_prep(const float* __restrict__ Wli, const float* __restrict__ Wih,
                       const float* __restrict__ Wnf, const float* __restrict__ Whh,
                       bf16* wli_h, bf16* wli_l, bf16* wih_h, bf16* wih_l,
                       bf16* wnf_h, bf16* wnf_l, bf16* whb) {
    const int n1 = Hh * 768, n2 = G4 * Hh, n3 = Hh * Ee, n4 = G4 * Hh;
    const int ntot = n1 + n2 + n3 + n4;
    for (int idx = blockIdx.x * 256 + threadIdx.x; idx < ntot; idx += gridDim.x * 256) {
        if (idx < n1 + n2 + n3) {
            const float* src; bf16 *dh, *dl; int j;
            if (idx < n1)           { src = Wli; dh = wli_h; dl = wli_l; j = idx; }
            else if (idx < n1 + n2) { src = Wih; dh = wih_h; dl = wih_l; j = idx - n1; }
            else                    { src = Wnf; dh = wnf_h; dl = wnf_l; j = idx - n1 - n2; }
            float x = src[j];
            bf16 h = (bf16)x;
            dh[j] = h;
            dl[j] = (bf16)(x - (float)h);
        } else {
            int j = idx - n1 - n2 - n3;
            whb[j] = (bf16)Whh[j];
        }
    }
}

// ============================================================
// k_gemm: split-bf16 (3-pass) 128x128x64-tile GEMM, 4 waves. (unchanged)
// ============================================================
template<int AMODE, int EPI, int KT, int NTOT>
__global__ __launch_bounds__(256, 2)
void k_gemm(const float* __restrict__ a0, const float* __restrict__ a1,
            const float* __restrict__ a2,
            const bf16* __restrict__ ah_src, const bf16* __restrict__ al_src,
            const bf16* __restrict__ bh_src, const bf16* __restrict__ bl_src,
            const float* __restrict__ bias0, const float* __restrict__ bias1,
            float* __restrict__ outf, bf16* __restrict__ outh, bf16* __restrict__ outl)
{
    __shared__ __align__(16) bf16 lA[2][128 * 64];
    __shared__ __align__(16) bf16 lB[2][128 * 64];
    const int tid = threadIdx.x;
    const int l = tid & 63, w = tid >> 6;
    const int wr = w >> 1, wc = w & 1;
    const int lr = l & 15, lh = l >> 4;
    const int mb = blockIdx.x;
    const int nb = blockIdx.y;

    f32x4 acc[4][4];
    #pragma unroll
    for (int i = 0; i < 4; ++i)
        #pragma unroll
        for (int j = 0; j < 4; ++j) acc[i][j] = {};

    for (int ks = 0; ks < KT / 64; ++ks) {
        #pragma unroll
        for (int p = 0; p < 4; ++p) {
            int Gi = p * 256 + tid;
            int row = Gi >> 3, gsl = Gi & 7;
            int k = ks * 64 + gsl * 8;
            int dst = row * 64 + ((gsl ^ (row & 7)) * 8);
            if constexpr (AMODE == 2) {
                size_t base = (size_t)(mb * 128 + row) * KT + k;
                *(bf16x8*)&lA[0][dst] = *(const bf16x8*)(ah_src + base);
                *(bf16x8*)&lA[1][dst] = *(const bf16x8*)(al_src + base);
            } else {
                const float* src; int e;
                if constexpr (AMODE == 0) {
                    int seg = k >> 8; e = k & 255;
                    src = (seg == 0) ? a0 : (seg == 1) ? a1 : a2;
                } else { src = a0; e = k; }
                size_t base = ((size_t)row * Tt + mb) * Ee + e;
                float4 v0 = *(const float4*)(src + base);
                float4 v1 = *(const float4*)(src + base + 4);
                float vv[8] = {v0.x, v0.y, v0.z, v0.w, v1.x, v1.y, v1.z, v1.w};
                bf16x8 hv, lv;
                #pragma unroll
                for (int j = 0; j < 8; ++j) {
                    bf16 h = (bf16)vv[j];
                    hv[j] = h;
                    lv[j] = (bf16)(vv[j] - (float)h);
                }
                *(bf16x8*)&lA[0][dst] = hv;
                *(bf16x8*)&lA[1][dst] = lv;
            }
            size_t bbase = (size_t)(nb * 128 + row) * KT + k;
            *(bf16x8*)&lB[0][dst] = *(const bf16x8*)(bh_src + bbase);
            *(bf16x8*)&lB[1][dst] = *(const bf16x8*)(bl_src + bbase);
        }
        __syncthreads();
        #pragma unroll
        for (int kt = 0; kt < 2; ++kt) {
            bf16x8 ah[4], al[4], bh[4], bl[4];
            #pragma unroll
            for (int mt = 0; mt < 4; ++mt) {
                int row = wr * 64 + mt * 16 + lr;
                int g = (kt * 4 + lh) ^ (row & 7);
                ah[mt] = *(const bf16x8*)&lA[0][row * 64 + g * 8];
                al[mt] = *(const bf16x8*)&lA[1][row * 64 + g * 8];
            }
            #pragma unroll
            for (int nt = 0; nt < 4; ++nt) {
                int row = wc * 64 + nt * 16 + lr;
                int g = (kt * 4 + lh) ^ (row & 7);
                bh[nt] = *(const bf16x8*)&lB[0][row * 64 + g * 8];
                bl[nt] = *(const bf16x8*)&lB[1][row * 64 + g * 8];
            }
            #pragma unroll
            for (int mt = 0; mt < 4; ++mt)
                #pragma unroll
                for (int nt = 0; nt < 4; ++nt) {
                    acc[mt][nt] = MFMA16(ah[mt], bh[nt], acc[mt][nt]);
                    acc[mt][nt] = MFMA16(ah[mt], bl[nt], acc[mt][nt]);
                    acc[mt][nt] = MFMA16(al[mt], bh[nt], acc[mt][nt]);
                }
        }
        __syncthreads();
    }
    if constexpr (EPI == 1) {
        // packed store: xph[((t*8 + bgrp)*1024 + n)*16 + bi], contiguous 512B/wave
        #pragma unroll
        for (int nt = 0; nt < 4; ++nt) {
            int n = nb * 128 + wc * 64 + nt * 16 + lr;
            float bv = bias0[n] + bias1[n];
            #pragma unroll
            for (int mt = 0; mt < 4; ++mt) {
                int bq = wr * 4 + mt;
                u16x4 pk;
                #pragma unroll
                for (int r = 0; r < 4; ++r)
                    pk[r] = f2bbits((bf16)(acc[mt][nt][r] + bv));
                *(u16x4*)(outh + (((size_t)mb * 8 + bq) * 1024 + n) * 16 + lh * 4) = pk;
            }
        }
    } else {
        #pragma unroll
        for (int nt = 0; nt < 4; ++nt) {
            int n = nb * 128 + wc * 64 + nt * 16 + lr;
            float bv = bias0[n];
            #pragma unroll
            for (int mt = 0; mt < 4; ++mt)
                #pragma unroll
                for (int r = 0; r < 4; ++r) {
                    int m = mb * 128 + wr * 64 + mt * 16 + lh * 4 + r;
                    float v = acc[mt][nt][r] + bv;
                    if constexpr (EPI == 0) {
                        bf16 h = (bf16)v;
                        outh[(size_t)m * NTOT + n] = h;
                        outl[(size_t)m * NTOT + n] = (bf16)(v - (float)h);
                    } else {
                        outf[(size_t)m * NTOT + n] = fmaxf(v, 0.f);
                    }
                }
        }
    }
}

// ============================================================
// k_lstm: 32 WGs = 8 batch groups x 4 participants. Participant c owns
// units [64c,64c+64) x all 4 gates = 256 W rows = 128 regs/lane, FULLY
// VGPR-resident (4 waves x 16 units; __launch_bounds__(256,1) -> 512-reg
// budget, demand ~210 -> no remat, proven allocatable in round 11).
// ZERO per-step weight motion. Per step: poll 3 remote flags (relaxed,
// no cache-maintenance) -> stage h_{t-1} (16KB) from XCD L2 into LDS
// (bf16, rotation swizzle) -> 32 MFMA vs resident W -> in-register c/h
// update -> h stores (relaxed agent) -> vmcnt(0) -> barrier -> flag++.
// Mapping g=blk&7 co-locates a group's 4 WGs on one XCD (round-robin).
// ============================================================
__global__ __launch_bounds__(256, 1)
void k_lstm(const bf16* __restrict__ whb, const bf16* __restrict__ xph,
            float* __restrict__ hexch, unsigned int* __restrict__ flags)
{
    __shared__ __align__(16) bf16 hstage[16 * 256];   // 8KB: staged h_{t-1}
    const int tid = threadIdx.x;
    const int l = tid & 63, w = tid >> 6;             // wave 0..3
    const int lr = l & 15, lh = l >> 4;
    const int g = blockIdx.x & 7;                     // batch group (one XCD under %8)
    const int c = blockIdx.x >> 3;                    // participant: units [64c,64c+64)

    const int ju = c * 64 + w * 16 + lr;              // this lane's unit (gate col)

    // ---- resident W_hh slice: 4 gates x 8 kt x 4 regs = 128 VGPRs ----
    f32x4 wf[4][8];
    #pragma unroll
    for (int q = 0; q < 4; ++q)
        #pragma unroll
        for (int kt = 0; kt < 8; ++kt)
            wf[q][kt] = *(const f32x4*)(whb + (size_t)(q * 256 + ju) * 256 + kt * 32 + lh * 8);

    unsigned int* selfflag = flags + (g * 4 + c) * 16;
    f32x4 cst = {};

    for (int t = 0; t < Tt; ++t) {
        f32x4 acc[4] = {};
        u16x4 xq[4];
        const bf16* xb = xph + (size_t)(t * 8 + g) * 1024 * 16;

        if (t > 0) {
            // wait for the other 3 participants to publish h_{t-1}
            if (l < 4 && l != c) {
                const unsigned int* fp = flags + (g * 4 + l) * 16;
                while (__hip_atomic_load(fp, __ATOMIC_RELAXED, __HIP_MEMORY_SCOPE_AGENT) < (unsigned)t)
                    __builtin_amdgcn_s_sleep(1);
            }
            asm volatile("" ::: "memory");   // don't hoist h loads above the poll

            // cooperative stage h_{t-1} (16x256 f32 from L2) -> hstage bf16, swizzled
            {
                int m = tid >> 4, j0 = (tid & 15) * 16;
                const float* hp = hexch + ((size_t)(g * Tt + (t - 1)) * 16 + m) * 256 + j0;
                union { unsigned long long u[8]; float f[16]; } hv;
                #pragma unroll
                for (int jj = 0; jj < 8; ++jj)
                    hv.u[jj] = __hip_atomic_load((const unsigned long long*)(hp + jj * 2),
                                                 __ATOMIC_RELAXED, __HIP_MEMORY_SCOPE_AGENT);
                bf16x8 p0, p1;
                #pragma unroll
                for (int jj = 0; jj < 8; ++jj) { p0[jj] = (bf16)hv.f[jj]; p1[jj] = (bf16)hv.f[8 + jj]; }
                int gk0 = j0 >> 3;
                *(bf16x8*)&hstage[m * 256 + (((gk0)     + m) & 31) * 8] = p0;
                *(bf16x8*)&hstage[m * 256 + (((gk0 + 1) + m) & 31) * 8] = p1;
            }
            asm volatile("s_waitcnt lgkmcnt(0)\n\ts_barrier" ::: "memory");

            #pragma unroll
            for (int kt = 0; kt < 8; ++kt) {
                bf16x8 af = *(const bf16x8*)&hstage[lr * 256 + ((kt * 4 + lh + lr) & 31) * 8];
                if (kt == 4) {   // xq issue: latency hidden under kt=4..7
                    #pragma unroll
                    for (int q = 0; q < 4; ++q)
                        xq[q] = *(const u16x4*)(xb + (size_t)(q * 256 + ju) * 16 + lh * 4);
                }
                #pragma unroll
                for (int q = 0; q < 4; ++q)
                    acc[q] = MFMA16(af, __builtin_bit_cast(bf16x8, wf[q][kt]), acc[q]);
            }
        } else {
            #pragma unroll
            for (int q = 0; q < 4; ++q)
                xq[q] = *(const u16x4*)(xb + (size_t)(q * 256 + ju) * 16 + lh * 4);
        }

        // ---- in-register LSTM update; h -> global f32 (agent-scope) ----
        float* hg = hexch + (size_t)(g * Tt + t) * 16 * 256;
        #pragma unroll
        for (int r = 0; r < 4; ++r) {
            float iv = acc[0][r] + b2f(xq[0][r]);
            float fv = acc[1][r] + b2f(xq[1][r]);
            float gv = acc[2][r] + b2f(xq[2][r]);
            float ov = acc[3][r] + b2f(xq[3][r]);
            float cn = sigm(fv) * cst[r] + sigm(iv) * tanh_(gv);
            cst[r] = cn;
            float hv = sigm(ov) * tanh_(cn);
            int m = lh * 4 + r;
            __hip_atomic_store(hg + (size_t)m * 256 + ju, hv,
                               __ATOMIC_RELAXED, __HIP_MEMORY_SCOPE_AGENT);
        }
        // drain own h stores, sync all waves, then publish
        asm volatile("s_waitcnt vmcnt(0)" ::: "memory");
        __syncthreads();
        if (tid == 0)
            __hip_atomic_fetch_add(selfflag, 1u, __ATOMIC_RELAXED, __HIP_MEMORY_SCOPE_AGENT);
    }
}

// ============================================================
// k_attn: one wave per (b,t). 9 dot products + att softmax, all f32.
// ============================================================
DEV float wred(float v) {
    #pragma unroll
    for (int off = 32; off > 0; off >>= 1) v += __shfl_down(v, off, 64);
    return v;
}

__global__ __launch_bounds__(256, 4)
void k_attn(const float* __restrict__ hexch, const float* __restrict__ ntr,
            const int* __restrict__ hidx,
            const float* __restrict__ a1w, const float* __restrict__ a1b,
            const float* __restrict__ a2w, const float* __restrict__ a2b,
            float* __restrict__ out)
{
    int wid = blockIdx.x * 4 + (threadIdx.x >> 6);
    if (wid >= Mm) return;
    int l = threadIdx.x & 63;
    int t = wid / Bb, b = wid % Bb;
    int g = b >> 4, bi = b & 15;

    float4 nt4 = *(const float4*)(ntr + (size_t)wid * 256 + l * 4);
    float4 w14 = *(const float4*)(a1w + l * 4);
    float4 w24 = *(const float4*)(a2w + l * 4);
    float lg[9], fh[9];
    float fn = nt4.x * w24.x + nt4.y * w24.y + nt4.z * w24.z + nt4.w * w24.w;
    #pragma unroll
    for (int k = 0; k < 9; ++k) {
        int ts = (k == 0) ? t : hidx[((size_t)b * Tt + t) * 8 + (k - 1)];
        const float* hrow = hexch + ((size_t)(g * Tt + ts) * 16 + bi) * 256;
        float4 h4 = *(const float4*)(hrow + l * 4);
        lg[k] = h4.x * nt4.x + h4.y * nt4.y + h4.z * nt4.z + h4.w * nt4.w;
        fh[k] = h4.x * w14.x + h4.y * w14.y + h4.z * w14.z + h4.w * w14.w;
    }
    #pragma unroll
    for (int k = 0; k < 9; ++k) { lg[k] = wred(lg[k]); fh[k] = wred(fh[k]); }
    fn = wred(fn);
    if (l == 0) {
        float f2 = fn + a2b[0], b1 = a1b[0];
        float tv[9], mx = -1e30f;
        #pragma unroll
        for (int k = 0; k < 9; ++k) { tv[k] = tanh_(fh[k] + b1 + f2); mx = fmaxf(mx, tv[k]); }
        float s = 0.f, accv = 0.f;
        #pragma unroll
        for (int k = 0; k < 9; ++k) { float e = __expf(tv[k] - mx); s += e; accv += e * lg[k]; }
        out[(size_t)b * Tt + t] = accv / s;
    }
}

// ============================================================
extern "C" void kernel_launch(void* const* d_in, const int* in_sizes, int n_in,
                              void* d_out, int out_size, void* d_ws, size_t ws_size,
                              hipStream_t stream)
{
    const float* q   = (const float*)d_in[0];
    const float* nq  = (const float*)d_in[1];
    const float* sk  = (const float*)d_in[2];
    const float* an  = (const float*)d_in[3];
    const int*   hid = (const int*)d_in[4];
    const float* Wnf = (const float*)d_in[5];
    const float* bnf = (const float*)d_in[6];
    const float* Wli = (const float*)d_in[7];
    const float* bli = (const float*)d_in[8];
    const float* Wih = (const float*)d_in[9];
    const float* Whh = (const float*)d_in[10];
    const float* bih = (const float*)d_in[11];
    const float* bhh = (const float*)d_in[12];
    const float* a1w = (const float*)d_in[13];
    const float* a1b = (const float*)d_in[14];
    const float* a2w = (const float*)d_in[15];
    const float* a2b = (const float*)d_in[16];
    float* out = (float*)d_out;

    char* ws = (char*)d_ws;   // needs ~133 MiB (WS_NEED)
    unsigned int* flags = (unsigned int*)(ws + OFF_FLAGS);
    bf16* wli_h = (bf16*)(ws + OFF_WLI_H);
    bf16* wli_l = (bf16*)(ws + OFF_WLI_L);
    bf16* wih_h = (bf16*)(ws + OFF_WIH_H);
    bf16* wih_l = (bf16*)(ws + OFF_WIH_L);
    bf16* wnf_h = (bf16*)(ws + OFF_WNF_H);
    bf16* wnf_l = (bf16*)(ws + OFF_WNF_L);
    bf16* whb   = (bf16*)(ws + OFF_WHB);
    bf16* xin_h = (bf16*)(ws + OFF_XIN_H);
    bf16* xin_l = (bf16*)(ws + OFF_XIN_L);
    bf16* xph   = (bf16*)(ws + OFF_XPH);
    float* hex  = (float*)(ws + OFF_HEX);
    float* ntr  = (float*)(ws + OFF_NTR);

    k_reset<<<2, 256, 0, stream>>>(flags);
    k_prep<<<512, 256, 0, stream>>>(Wli, Wih, Wnf, Whh, wli_h, wli_l, wih_h, wih_l,
                                    wnf_h, wnf_l, whb);

    // x_in (hi/lo) = [q|ans|skill] @ W_li^T + b_li     (M x 256, K=768)
    dim3 g1(Tt, 2);
    k_gemm<0, 0, 768, 256><<<g1, 256, 0, stream>>>(q, an, sk, nullptr, nullptr,
        wli_h, wli_l, bli, nullptr, nullptr, xin_h, xin_l);

    // xp(bf16) = x_in @ W_ih^T + (b_ih + b_hh), packed [t][bgrp][n][16]
    dim3 g2(Tt, 8);
    k_gemm<2, 1, 256, 1024><<<g2, 256, 0, stream>>>(nullptr, nullptr, nullptr, xin_h, xin_l,
        wih_h, wih_l, bih, bhh, nullptr, xph, nullptr);

    // next_trans = relu(nq @ W_nf^T + b_nf)            (M x 256, K=256)
    dim3 g3(Tt, 2);
    k_gemm<1, 2, 256, 256><<<g3, 256, 0, stream>>>(nq, nullptr, nullptr, nullptr, nullptr,
        wnf_h, wnf_l, bnf, nullptr, ntr, nullptr, nullptr);

    k_lstm<<<32, 256, 0, stream>>>(whb, xph, hex, flags);

    k_attn<<<Mm / 4, 256, 0, stream>>>(hex, ntr, hid, a1w, a1b, a2w, a2b, out);
    (void)in_sizes; (void)n_in; (void)out_size; (void)ws_size;
}